// Round 6
// baseline (1041.714 us; speedup 1.0000x reference)
//
#include <hip/hip_runtime.h>
#include <hip/hip_bf16.h>
#include <math.h>

using bf16 = __hip_bfloat16;
typedef __attribute__((ext_vector_type(8))) short short8;
typedef __attribute__((ext_vector_type(4))) float f32x4;

constexpr int nB = 1024, nS = 30, nE = 300, nD = 512, nH = 8, nL = 4, nDK = 64;
constexpr int nTOK = nB * nS;  // 30720
constexpr float kSqrtD = 22.627416997969522f;
constexpr float kPEc   = -0.03597789207803244f;  // -2*ln(10000)/512
constexpr float kEps   = 1e-5f;

__device__ inline unsigned short bfbits(float f) {
  bf16 h = __float2bfloat16(f);
  return *(unsigned short*)&h;
}
__device__ inline float b2f(short s) {
  return __uint_as_float(((unsigned)(unsigned short)s) << 16);
}
__device__ inline void gload16(const void* g, void* lds) {
  __builtin_amdgcn_global_load_lds(
      (const __attribute__((address_space(1))) unsigned int*)g,
      (__attribute__((address_space(3))) unsigned int*)lds, 16, 0, 0);
}
// combine 2-block partial stats -> (mu, rsqrt(var+eps))
__device__ inline float2 rowstat(const float* p, int r) {
  float2 a = ((const float2*)p)[r];
  float2 b = ((const float2*)p)[nTOK + r];
  float s = a.x + b.x, q = a.y + b.y;
  float mu = s * (1.f / nD);
  float var = q * (1.f / nD) - mu * mu;
  return make_float2(mu, rsqrtf(var + kEps));
}

// ---------------- one-shot weight convert + pe table ----------------
__global__ __launch_bounds__(256) void cvt_all(
    const float* __restrict__ Wo, const float* __restrict__ Wfc,
    const float* __restrict__ Wq, const float* __restrict__ Wk,
    const float* __restrict__ Wv, const float* __restrict__ Win,
    bf16* __restrict__ wo, bf16* __restrict__ wfc, bf16* __restrict__ wq,
    bf16* __restrict__ wk, bf16* __restrict__ wv, bf16* __restrict__ win,
    float* __restrict__ pe) {
  int i = blockIdx.x * 256 + threadIdx.x;
  if (i < 1048576) {
    wo[i] = __float2bfloat16(Wo[i]);
    wfc[i] = __float2bfloat16(Wfc[i]);
    return;
  }
  i -= 1048576;
  if (i < 16384) {
    wq[i] = __float2bfloat16(Wq[i]);
    wk[i] = __float2bfloat16(Wk[i]);
    wv[i] = __float2bfloat16(Wv[i]);
    return;
  }
  i -= 16384;
  if (i < 163840) {
    int r = i / 320, e = i - r * 320;
    win[i] = __float2bfloat16(e < nE ? Win[r * nE + e] : 0.f);
    return;
  }
  i -= 163840;
  if (i < 15360) {
    int s = i >> 9, d = i & 511;
    float ang = (float)s * expf((float)(d >> 1) * kPEc);
    pe[i] = (d & 1) ? cosf(ang) : sinf(ang);
  }
}

// gather emb rows -> bf16 [nTOK][320] (K padded 300->320 with zeros)
__global__ __launch_bounds__(256) void gather_kernel(const int* __restrict__ x,
                                                     const float* __restrict__ emb,
                                                     bf16* __restrict__ a) {
  int g = blockIdx.x * 256 + threadIdx.x;  // 30720*40 slots
  int t = g / 40, ch = g - 40 * t;
  float4 v0 = make_float4(0.f, 0.f, 0.f, 0.f), v1 = v0;
  const float* src = emb + (size_t)x[t] * nE + ch * 8;
  if (ch < 37) { v0 = *(const float4*)src; v1 = *(const float4*)(src + 4); }
  else if (ch == 37) { v0 = *(const float4*)src; }
  ushort4 u0, u1;
  u0.x = bfbits(v0.x); u0.y = bfbits(v0.y); u0.z = bfbits(v0.z); u0.w = bfbits(v0.w);
  u1.x = bfbits(v1.x); u1.y = bfbits(v1.y); u1.z = bfbits(v1.z); u1.w = bfbits(v1.w);
  bf16* dst = a + (size_t)t * 320 + ch * 8;
  *(ushort4*)dst = u0;
  *(ushort4*)(dst + 4) = u1;
}

// ---------------- MFMA GEMM 64x256 tile, deferred-LN plumbing ----------------
// C[M,512] = A @ W^T; LNIN: A-rows get LN(statsA,gA,bA) applied at staging.
// PE=1: out = (acc+bias)*sqrtD + pe.  PE=0: out = acc + bias? + resid',
//   resid' = affine(resid, statsR, gR, bR) if psR else raw resid.
// pstatOut (optional): per-row (sum, sumsq) partials over this block's 256 cols.
template <int KA, int LNIN, int PE>
__global__ __launch_bounds__(256, 3) void gemm_ln(
    const bf16* __restrict__ A, const bf16* __restrict__ W,
    const float* __restrict__ bias, const bf16* __restrict__ resid,
    const float* __restrict__ psA, const float* __restrict__ gA,
    const float* __restrict__ bA, const float* __restrict__ psR,
    const float* __restrict__ gR, const float* __restrict__ bR,
    const float* __restrict__ pe, float* __restrict__ pstatOut,
    bf16* __restrict__ out) {
  __shared__ __align__(16) char smem[46080];  // 2x20480 buf + 4096 gb + 512 stA + 512 stR
  const int tid = threadIdx.x, lane = tid & 63, w = tid >> 6;
  const int q = lane >> 4, c = lane & 15;
  // XCD-paired swizzle: the 2 n-blocks sharing an A-tile get ids 8 apart
  const int bid = blockIdx.x;
  const int mb = (bid >> 4) * 8 + (bid & 7), nb = (bid >> 3) & 1;
  const int m0 = mb * 64, n0 = nb * 256;
  constexpr int NK = KA / 32;
  float* gbA = (float*)(smem + 40960);
  float* stA = (float*)(smem + 45056);
  float* stR = (float*)(smem + 45568);

  if (LNIN) {
    for (int i = tid; i < 512; i += 256) {
      gbA[2 * i] = gA[i];
      gbA[2 * i + 1] = bA[i];
    }
    if (tid < 64) {
      float2 s = rowstat(psA, m0 + tid);
      stA[2 * tid] = s.x;
      stA[2 * tid + 1] = s.y;
    }
  }
  if (!PE && psR && tid >= 64 && tid < 128) {
    float2 s = rowstat(psR, m0 + tid - 64);
    stR[2 * (tid - 64)] = s.x;
    stR[2 * (tid - 64) + 1] = s.y;
  }

  f32x4 acc[4][4];
#pragma unroll
  for (int i = 0; i < 4; ++i)
#pragma unroll
    for (int j = 0; j < 4; ++j) acc[i][j] = (f32x4){0.f, 0.f, 0.f, 0.f};

  const int arow = tid >> 2, akc = tid & 3;
  const bf16* Athr = A + (size_t)(m0 + arow) * KA + akc * 8;
  short8 areg;

  auto issue = [&](int ks, int buf) {
    char* base = smem + buf * 20480;
    if (LNIN) {
      areg = *(const short8*)(Athr + ks * 32);  // global -> reg (1 vmem)
    } else {
      gload16(A + (size_t)(m0 + lane) * KA + ks * 32 + w * 8, base + w * 1024);
    }
#pragma unroll
    for (int j = 0; j < 4; ++j) {
      const int idx = w * 4 + j, kc = idx & 3, cb = idx >> 2;
      gload16(W + (size_t)(n0 + cb * 64 + lane) * KA + ks * 32 + kc * 8,
              base + 4096 + kc * 4096 + cb * 1024);
    }
  };
  auto writeA = [&](int ks, int buf) {
    if (!LNIN) return;
    char* base = smem + buf * 20480;
    const float mu = stA[2 * arow], inv = stA[2 * arow + 1];
    const float* gb = &gbA[2 * (ks * 32 + akc * 8)];
    short8 o;
#pragma unroll
    for (int j = 0; j < 8; ++j) {
      float xv = b2f(areg[j]);
      o[j] = (short)bfbits((xv - mu) * inv * gb[2 * j] + gb[2 * j + 1]);
    }
    *(short8*)(base + (akc * 64 + arow) * 16) = o;
  };

  issue(0, 0);
  __syncthreads();  // stA/gbA/stR visible
  writeA(0, 0);
  for (int ks = 0; ks < NK; ++ks) {
    const int cur = ks & 1;
    if (ks + 1 < NK) {
      issue(ks + 1, cur ^ 1);
      asm volatile("s_waitcnt vmcnt(5) lgkmcnt(0)" ::: "memory");
    } else {
      asm volatile("s_waitcnt vmcnt(0) lgkmcnt(0)" ::: "memory");
    }
    __builtin_amdgcn_s_barrier();
    asm volatile("" ::: "memory");
    const bf16* As = (const bf16*)(smem + cur * 20480);
    const bf16* Ws = (const bf16*)(smem + cur * 20480 + 4096);
    short8 af[4], bfr[4];
#pragma unroll
    for (int mt = 0; mt < 4; ++mt)
      af[mt] = *(const short8*)(As + (q * 64 + mt * 16 + c) * 8);
#pragma unroll
    for (int nt = 0; nt < 4; ++nt)
      bfr[nt] = *(const short8*)(Ws + (q * 256 + w * 64 + nt * 16 + c) * 8);
    if (ks + 1 < NK) writeA(ks + 1, cur ^ 1);
#pragma unroll
    for (int mt = 0; mt < 4; ++mt)
#pragma unroll
      for (int nt = 0; nt < 4; ++nt)
        acc[mt][nt] = __builtin_amdgcn_mfma_f32_16x16x32_bf16(af[mt], bfr[nt], acc[mt][nt], 0, 0, 0);
    asm volatile("s_waitcnt lgkmcnt(0)" ::: "memory");
    __builtin_amdgcn_s_barrier();
    asm volatile("" ::: "memory");
  }

  // ---- epilogue: two 32-row halves through an LDS transpose ----
  float* tb = (float*)smem;  // [32][260] fp32 = 33280 B (buffers dead)
  const int lrow = tid >> 3, lcg = (tid & 7) * 32;
  const bool doR = (!PE) && (psR != nullptr);
  for (int hf = 0; hf < 2; ++hf) {
    if (hf) __syncthreads();
#pragma unroll
    for (int mtl = 0; mtl < 2; ++mtl) {
      const int mt = hf * 2 + mtl;
#pragma unroll
      for (int nt = 0; nt < 4; ++nt)
#pragma unroll
        for (int r = 0; r < 4; ++r)
          tb[(mtl * 16 + q * 4 + r) * 260 + w * 64 + nt * 16 + c] = acc[mt][nt][r];
    }
    __syncthreads();
    const int grow = m0 + hf * 32 + lrow;
    const int prow = grow % nS;
    float muR = 0.f, invR = 0.f;
    if (doR) {
      muR = stR[2 * (hf * 32 + lrow)];
      invR = stR[2 * (hf * 32 + lrow) + 1];
    }
    float s = 0.f, sq = 0.f;
#pragma unroll
    for (int j = 0; j < 8; ++j) {
      const int col = n0 + lcg + j * 4;
      float4 v = *(float4*)&tb[lrow * 260 + lcg + j * 4];
      float e[4] = {v.x, v.y, v.z, v.w};
      if (bias) {
        const float4 bv = *(const float4*)(bias + col);
        e[0] += bv.x; e[1] += bv.y; e[2] += bv.z; e[3] += bv.w;
      }
      if (PE) {
        const float4 pv = *(const float4*)(pe + (size_t)prow * nD + col);
        e[0] = e[0] * kSqrtD + pv.x; e[1] = e[1] * kSqrtD + pv.y;
        e[2] = e[2] * kSqrtD + pv.z; e[3] = e[3] * kSqrtD + pv.w;
      } else {
        const ushort4 rv = *(const ushort4*)(resid + (size_t)grow * nD + col);
        float rf[4] = {b2f((short)rv.x), b2f((short)rv.y), b2f((short)rv.z), b2f((short)rv.w)};
        if (doR) {
          const float4 gv = *(const float4*)(gR + col);
          const float4 bv2 = *(const float4*)(bR + col);
          e[0] += (rf[0] - muR) * invR * gv.x + bv2.x;
          e[1] += (rf[1] - muR) * invR * gv.y + bv2.y;
          e[2] += (rf[2] - muR) * invR * gv.z + bv2.z;
          e[3] += (rf[3] - muR) * invR * gv.w + bv2.w;
        } else {
          e[0] += rf[0]; e[1] += rf[1]; e[2] += rf[2]; e[3] += rf[3];
        }
      }
      ushort4 o;
#pragma unroll
      for (int k = 0; k < 4; ++k) {
        const unsigned short u = bfbits(e[k]);
        ((unsigned short*)&o)[k] = u;
        const float t = b2f((short)u);  // stats consistent with stored bf16
        s += t; sq += t * t;
      }
      *(ushort4*)(out + (size_t)grow * nD + col) = o;
    }
    if (pstatOut) {
      s += __shfl_xor(s, 1); sq += __shfl_xor(sq, 1);
      s += __shfl_xor(s, 2); sq += __shfl_xor(sq, 2);
      s += __shfl_xor(s, 4); sq += __shfl_xor(sq, 4);
      if ((tid & 7) == 0)
        ((float2*)pstatOut)[(size_t)nb * nTOK + grow] = make_float2(s, sq);
    }
  }
}

// ---------------- fused attention per (batch, head); optional LN on input ----------------
__global__ __launch_bounds__(256) void attn_kernel(
    const bf16* __restrict__ wqb, const bf16* __restrict__ wkb,
    const bf16* __restrict__ wvb, const int* __restrict__ mask,
    const bf16* __restrict__ hin, const float* __restrict__ psIn,
    const float* __restrict__ gIn, const float* __restrict__ bIn,
    bf16* __restrict__ aout) {
  const int tid = threadIdx.x, lane = tid & 63, w = tid >> 6;
  const int q = lane >> 4, c = lane & 15;
  const int b = blockIdx.x >> 3, hd = blockIdx.x & 7;

  __shared__ __align__(16) bf16 xs[8][32][8];
  __shared__ __align__(16) bf16 wq[8][64][8];
  __shared__ __align__(16) bf16 wk[8][64][8];
  __shared__ __align__(16) bf16 wv[8][64][8];
  __shared__ __align__(16) bf16 qb[8][32][8];
  __shared__ __align__(16) bf16 kb[8][32][8];
  __shared__ __align__(16) bf16 vt[4][64][8];
  __shared__ __align__(16) bf16 pb[4][32][8];
  __shared__ float ps[32][33];
  __shared__ int msk[32];

  {  // stage x, LN-on-the-fly if psIn
    const int row = tid & 31, k8 = tid >> 5;
    uint4 z = make_uint4(0, 0, 0, 0);
    if (row < nS) {
      z = *(const uint4*)(hin + (size_t)(b * nS + row) * nD + hd * nDK + k8 * 8);
      if (psIn) {
        const float2 st = rowstat(psIn, b * nS + row);
        const int col = hd * nDK + k8 * 8;
        const float4 g0 = *(const float4*)(gIn + col);
        const float4 g1 = *(const float4*)(gIn + col + 4);
        const float4 b0 = *(const float4*)(bIn + col);
        const float4 b1 = *(const float4*)(bIn + col + 4);
        short8 xv = *(short8*)&z;
        float e[8];
#pragma unroll
        for (int j = 0; j < 8; ++j) e[j] = (b2f(xv[j]) - st.x) * st.y;
        e[0] = e[0] * g0.x + b0.x; e[1] = e[1] * g0.y + b0.y;
        e[2] = e[2] * g0.z + b0.z; e[3] = e[3] * g0.w + b0.w;
        e[4] = e[4] * g1.x + b1.x; e[5] = e[5] * g1.y + b1.y;
        e[6] = e[6] * g1.z + b1.z; e[7] = e[7] * g1.w + b1.w;
        short8 o;
#pragma unroll
        for (int j = 0; j < 8; ++j) o[j] = (short)bfbits(e[j]);
        z = *(uint4*)&o;
      }
    }
    *(uint4*)&xs[k8][row][0] = z;
  }
#pragma unroll
  for (int i = 0; i < 2; ++i) {
    const int s = tid + i * 256;
    const int row = s & 63, k8 = s >> 6;
    *(uint4*)&wq[k8][row][0] = *(const uint4*)(wqb + row * 64 + k8 * 8);
    *(uint4*)&wk[k8][row][0] = *(const uint4*)(wkb + row * 64 + k8 * 8);
    *(uint4*)&wv[k8][row][0] = *(const uint4*)(wvb + row * 64 + k8 * 8);
  }
  if (tid < nS) msk[tid] = mask[b * nS + tid];
  __syncthreads();

  f32x4 aq[2], ak[2], av[2];
#pragma unroll
  for (int mt = 0; mt < 2; ++mt) {
    aq[mt] = (f32x4){0.f, 0.f, 0.f, 0.f};
    ak[mt] = aq[mt]; av[mt] = aq[mt];
  }
#pragma unroll
  for (int kc = 0; kc < 2; ++kc) {
    short8 xa0 = *(const short8*)&xs[kc * 4 + q][c][0];
    short8 xa1 = *(const short8*)&xs[kc * 4 + q][16 + c][0];
    short8 wqf = *(const short8*)&wq[kc * 4 + q][w * 16 + c][0];
    short8 wkf = *(const short8*)&wk[kc * 4 + q][w * 16 + c][0];
    short8 wvf = *(const short8*)&wv[kc * 4 + q][w * 16 + c][0];
    aq[0] = __builtin_amdgcn_mfma_f32_16x16x32_bf16(xa0, wqf, aq[0], 0, 0, 0);
    aq[1] = __builtin_amdgcn_mfma_f32_16x16x32_bf16(xa1, wqf, aq[1], 0, 0, 0);
    ak[0] = __builtin_amdgcn_mfma_f32_16x16x32_bf16(xa0, wkf, ak[0], 0, 0, 0);
    ak[1] = __builtin_amdgcn_mfma_f32_16x16x32_bf16(xa1, wkf, ak[1], 0, 0, 0);
    av[0] = __builtin_amdgcn_mfma_f32_16x16x32_bf16(xa0, wvf, av[0], 0, 0, 0);
    av[1] = __builtin_amdgcn_mfma_f32_16x16x32_bf16(xa1, wvf, av[1], 0, 0, 0);
  }
  const int dk = w * 16 + c;
#pragma unroll
  for (int mt = 0; mt < 2; ++mt)
#pragma unroll
    for (int r = 0; r < 4; ++r) {
      const int i = mt * 16 + q * 4 + r;
      qb[dk >> 3][i][dk & 7] = __float2bfloat16(aq[mt][r]);
      kb[dk >> 3][i][dk & 7] = __float2bfloat16(ak[mt][r]);
      vt[i >> 3][dk][i & 7] = __float2bfloat16(av[mt][r]);
    }
  __syncthreads();

  {
    f32x4 sc = (f32x4){0.f, 0.f, 0.f, 0.f};
    const int is0 = (w >> 1) * 16, js0 = (w & 1) * 16;
#pragma unroll
    for (int kc = 0; kc < 2; ++kc) {
      short8 a = *(const short8*)&qb[kc * 4 + q][is0 + c][0];
      short8 bb = *(const short8*)&kb[kc * 4 + q][js0 + c][0];
      sc = __builtin_amdgcn_mfma_f32_16x16x32_bf16(a, bb, sc, 0, 0, 0);
    }
    const int j = js0 + c;
    const bool live = (j < nS) && (msk[j] != 0);
#pragma unroll
    for (int r = 0; r < 4; ++r) {
      const int i = is0 + q * 4 + r;
      ps[i][j] = live ? sc[r] * 0.125f : -1e9f;
    }
  }
  __syncthreads();

  if (tid < nS * 8) {
    const int r = tid >> 3, cc = tid & 7;
    float m = -1e30f;
    for (int j = cc; j < nS; j += 8) m = fmaxf(m, ps[r][j]);
#pragma unroll
    for (int o = 1; o < 8; o <<= 1) m = fmaxf(m, __shfl_xor(m, o));
    float sum = 0.f;
    for (int j = cc; j < nS; j += 8) sum += __expf(ps[r][j] - m);
#pragma unroll
    for (int o = 1; o < 8; o <<= 1) sum += __shfl_xor(sum, o);
    const float inv = 1.f / sum;
    for (int j = cc; j < nS; j += 8)
      pb[j >> 3][r][j & 7] = __float2bfloat16(__expf(ps[r][j] - m) * inv);
    if (cc >= 6) pb[3][r][cc] = __float2bfloat16(0.f);
  }
  __syncthreads();

  {
    f32x4 o0 = (f32x4){0.f, 0.f, 0.f, 0.f}, o1 = o0;
    short8 pa0 = *(const short8*)&pb[q][c][0];
    short8 pa1 = *(const short8*)&pb[q][16 + c][0];
    short8 vb = *(const short8*)&vt[q][w * 16 + c][0];
    o0 = __builtin_amdgcn_mfma_f32_16x16x32_bf16(pa0, vb, o0, 0, 0, 0);
    o1 = __builtin_amdgcn_mfma_f32_16x16x32_bf16(pa1, vb, o1, 0, 0, 0);
#pragma unroll
    for (int r = 0; r < 4; ++r) {
      const int i0 = q * 4 + r;
      aout[(size_t)(b * nS + i0) * nD + hd * nDK + dk] = __float2bfloat16(o0[r]);
      const int i1 = 16 + q * 4 + r;
      if (i1 < nS)
        aout[(size_t)(b * nS + i1) * nD + hd * nDK + dk] = __float2bfloat16(o1[r]);
    }
  }
}

// ---------------- final LN: affine(t2, stats) -> fp32 d_out ----------------
__global__ __launch_bounds__(256) void fln(const bf16* __restrict__ X,
                                           const float* __restrict__ ps,
                                           const float* __restrict__ g,
                                           const float* __restrict__ bta,
                                           float* __restrict__ Y) {
  const int w = threadIdx.x >> 6, lane = threadIdx.x & 63;
  const int row = blockIdx.x * 4 + w;
  const float2 st = rowstat(ps, row);
  const short8 v = *(const short8*)(X + (size_t)row * nD + lane * 8);
  const float4 g0 = *(const float4*)(g + lane * 8);
  const float4 g1 = *(const float4*)(g + lane * 8 + 4);
  const float4 b0 = *(const float4*)(bta + lane * 8);
  const float4 b1 = *(const float4*)(bta + lane * 8 + 4);
  float e[8];
#pragma unroll
  for (int j = 0; j < 8; ++j) e[j] = (b2f(v[j]) - st.x) * st.y;
  float* p = Y + (size_t)row * nD + lane * 8;
  *(float4*)p = make_float4(e[0] * g0.x + b0.x, e[1] * g0.y + b0.y,
                            e[2] * g0.z + b0.z, e[3] * g0.w + b0.w);
  *(float4*)(p + 4) = make_float4(e[4] * g1.x + b1.x, e[5] * g1.y + b1.y,
                                  e[6] * g1.z + b1.z, e[7] * g1.w + b1.w);
}

extern "C" void kernel_launch(void* const* d_in, const int* in_sizes, int n_in,
                              void* d_out, int out_size, void* d_ws, size_t ws_size,
                              hipStream_t stream) {
  const int*   x    = (const int*)d_in[0];
  const int*   mask = (const int*)d_in[1];
  const float* emb  = (const float*)d_in[2];
  const float* W_in = (const float*)d_in[3];
  const float* b_in = (const float*)d_in[4];
  const float* Wq   = (const float*)d_in[5];
  const float* Wk   = (const float*)d_in[6];
  const float* Wv   = (const float*)d_in[7];
  const float* Wo   = (const float*)d_in[8];
  const float* Wfc  = (const float*)d_in[9];
  const float* bfc  = (const float*)d_in[10];
  const float* g1   = (const float*)d_in[11];
  const float* be1  = (const float*)d_in[12];
  const float* g2   = (const float*)d_in[13];
  const float* be2  = (const float*)d_in[14];

  char* ws = (char*)d_ws;
  bf16* wo_b  = (bf16*)ws;                    // 2,097,152 B
  bf16* wfc_b = (bf16*)(ws + 2097152);        // 2,097,152
  bf16* wq_b  = (bf16*)(ws + 4194304);        // 32,768
  bf16* wk_b  = (bf16*)(ws + 4227072);        // 32,768
  bf16* wv_b  = (bf16*)(ws + 4259840);        // 32,768
  bf16* win_b = (bf16*)(ws + 4292608);        // 327,680
  float* pe   = (float*)(ws + 4620288);       // 61,440
  bf16* a_emb = (bf16*)(ws + 4681728);        // 19,660,800
  bf16* o_buf = (bf16*)(ws + 24342528);       // 31,457,280
  bf16* t1    = (bf16*)(ws + 55799808);       // 31,457,280
  bf16* t2a   = (bf16*)(ws + 87257088);       // 31,457,280
  bf16* t2b   = (bf16*)(ws + 118714368);      // 31,457,280
  float* pstat1 = (float*)(ws + 150171648);   // 491,520
  float* pstat2 = (float*)(ws + 150663168);   // 491,520
  bf16* t2[2] = {t2a, t2b};

  cvt_all<<<4860, 256, 0, stream>>>(Wo, Wfc, Wq, Wk, Wv, W_in, wo_b, wfc_b,
                                    wq_b, wk_b, wv_b, win_b, pe);
  gather_kernel<<<4800, 256, 0, stream>>>(x, emb, a_emb);

  // h0 = (emb@Win + b_in)*sqrtD + pe  -> t2[0]
  gemm_ln<320, 0, 1><<<960, 256, 0, stream>>>(
      a_emb, win_b, b_in, nullptr, nullptr, nullptr, nullptr, nullptr, nullptr,
      nullptr, pe, nullptr, t2[0]);

  const float* psPrev = nullptr;
  const float* gPrev = nullptr;
  const float* bPrev = nullptr;
  for (int l = 0; l < nL; ++l) {
    bf16* tin = t2[l & 1];
    bf16* tout = t2[(l + 1) & 1];
    // attention on h = affine(tin) (raw for l==0)
    attn_kernel<<<nB * nH, 256, 0, stream>>>(
        wq_b + l * 4096, wk_b + l * 4096, wv_b + l * 4096, mask, tin, psPrev,
        gPrev, bPrev, o_buf);
    // t1 = o @ Wo^T + affine(tin)   (+ row-stat partials)
    gemm_ln<512, 0, 0><<<960, 256, 0, stream>>>(
        o_buf, wo_b + (size_t)l * 262144, nullptr, tin, nullptr, nullptr,
        nullptr, psPrev, gPrev, bPrev, nullptr, pstat1, t1);
    // t2 = LN1(t1) @ Wfc^T + bfc + LN1(t1)   (+ row-stat partials)
    gemm_ln<512, 1, 0><<<960, 256, 0, stream>>>(
        t1, wfc_b + (size_t)l * 262144, bfc + l * nD, t1, pstat1, g1 + l * nD,
        be1 + l * nD, pstat1, g1 + l * nD, be1 + l * nD, nullptr, pstat2, tout);
    psPrev = pstat2;
    gPrev = g2 + l * nD;
    bPrev = be2 + l * nD;
  }
  fln<<<nTOK / 4, 256, 0, stream>>>(t2[nL & 1], pstat2, g2 + (nL - 1) * nD,
                                    be2 + (nL - 1) * nD, (float*)d_out);
  (void)in_sizes; (void)n_in; (void)out_size; (void)ws_size;
}